// Round 1
// baseline (287.714 us; speedup 1.0000x reference)
//
#include <hip/hip_runtime.h>
#include <hip/hip_bf16.h>
#include <cstdint>
#include <cstddef>

#define B_ 2
#define N_ 2048
#define D_ 1024
#define H_ 16
#define DH_ 64
#define XYROWS 4095   /* N + (N-1) */
#define NL 12         /* self + 11 tree neighbors */

typedef __attribute__((ext_vector_type(8))) short bf16x8;
typedef __attribute__((ext_vector_type(4))) float f32x4;

__device__ __forceinline__ float bf2f(unsigned short u) {
    union { unsigned int i; float f; } v; v.i = ((unsigned int)u) << 16; return v.f;
}
__device__ __forceinline__ unsigned short f2bf(float f) {
    union { float f; unsigned int i; } v; v.f = f;
    unsigned int u = v.i;
    unsigned int r = u + 0x7FFFu + ((u >> 16) & 1u);   // RNE
    return (unsigned short)(r >> 16);
}

// ---------------- fp32 -> bf16 conversion (8 elems/thread) ----------------
__global__ void cvt_bf16(const float* __restrict__ src,
                         unsigned short* __restrict__ dst, int nchunks) {
    int c = blockIdx.x * blockDim.x + threadIdx.x;
    if (c >= nchunks) return;
    size_t i = (size_t)c * 8;
    float4 a = *(const float4*)(src + i);
    float4 b = *(const float4*)(src + i + 4);
    union { unsigned short us[8]; uint4 u4; } o;
    o.us[0] = f2bf(a.x); o.us[1] = f2bf(a.y); o.us[2] = f2bf(a.z); o.us[3] = f2bf(a.w);
    o.us[4] = f2bf(b.x); o.us[5] = f2bf(b.y); o.us[6] = f2bf(b.z); o.us[7] = f2bf(b.w);
    *(uint4*)(dst + i) = o.u4;
}

// ------------- build xy = concat(query, y) per batch, in bf16 -------------
__global__ void build_xy(const float* __restrict__ q, const float* __restrict__ y,
                         unsigned short* __restrict__ xy) {
    int c = blockIdx.x * blockDim.x + threadIdx.x;   // chunk of 8 elems
    int total = B_ * XYROWS * (D_ / 8);
    if (c >= total) return;
    int col8 = (c & (D_ / 8 - 1)) * 8;
    int rg = c >> 7;                                  // global row 0..B*4095-1
    int b = (rg >= XYROWS) ? 1 : 0;
    int r = rg - b * XYROWS;
    const float* src;
    if (r < N_) src = q + ((size_t)b * N_ + r) * D_ + col8;
    else        src = y + ((size_t)b * (N_ - 1) + (r - N_)) * D_ + col8;
    float4 a = *(const float4*)(src);
    float4 bb = *(const float4*)(src + 4);
    union { unsigned short us[8]; uint4 u4; } o;
    o.us[0] = f2bf(a.x);  o.us[1] = f2bf(a.y);  o.us[2] = f2bf(a.z);  o.us[3] = f2bf(a.w);
    o.us[4] = f2bf(bb.x); o.us[5] = f2bf(bb.y); o.us[6] = f2bf(bb.z); o.us[7] = f2bf(bb.w);
    *(uint4*)(xy + (size_t)rg * D_ + col8) = o.u4;
}

// --------------------------- bf16 GEMM: C = A @ W^T -----------------------
// A: M x 1024 bf16 row-major; W: 1024 x 1024 bf16 row-major (rows = out feat)
// 128x128 block tile, 4 waves (2x2), each wave 64x64 via 4x4 MFMA 16x16x32.
template<bool OUTF32, bool BIAS>
__global__ __launch_bounds__(256, 2)
void gemm_bt(const unsigned short* __restrict__ A, const unsigned short* __restrict__ W,
             void* __restrict__ Cv, const float* __restrict__ bias, int M,
             size_t strideA, size_t strideC) {
    constexpr int K = 1024, Nn = 1024;
    constexpr int BK = 64, LDSS = 72;   // 72 ushort = 144B stride (16B aligned, 2-way-max bank alias)
    __shared__ __align__(16) unsigned short la[128 * LDSS];
    __shared__ __align__(16) unsigned short lb[128 * LDSS];

    const unsigned short* Ab = A + (size_t)blockIdx.z * strideA;
    int tid = threadIdx.x;
    int row0 = blockIdx.x * 128;
    int col0 = blockIdx.y * 128;
    int wave = tid >> 6, lane = tid & 63;
    int wm = wave >> 1, wn = wave & 1;
    int q4 = lane >> 4, r = lane & 15;

    f32x4 acc[4][4];
    f32x4 zero = {0.f, 0.f, 0.f, 0.f};
#pragma unroll
    for (int i = 0; i < 4; i++)
#pragma unroll
        for (int j = 0; j < 4; j++) acc[i][j] = zero;

    for (int k0 = 0; k0 < K; k0 += BK) {
#pragma unroll
        for (int p = 0; p < 4; p++) {
            int slot = p * 256 + tid;
            int row = slot >> 3;
            int c8 = (slot & 7) * 8;
            int ar = row0 + row; if (ar >= M) ar = M - 1;   // clamp (pad rows unused)
            uint4 va = *(const uint4*)(Ab + (size_t)ar * K + k0 + c8);
            uint4 vb = *(const uint4*)(W + (size_t)(col0 + row) * K + k0 + c8);
            *(uint4*)(&la[row * LDSS + c8]) = va;
            *(uint4*)(&lb[row * LDSS + c8]) = vb;
        }
        __syncthreads();
#pragma unroll
        for (int ks = 0; ks < 2; ks++) {
            bf16x8 af[4], bfv[4];
#pragma unroll
            for (int i = 0; i < 4; i++)
                af[i] = *(const bf16x8*)(&la[(wm * 64 + i * 16 + r) * LDSS + ks * 32 + q4 * 8]);
#pragma unroll
            for (int j = 0; j < 4; j++)
                bfv[j] = *(const bf16x8*)(&lb[(wn * 64 + j * 16 + r) * LDSS + ks * 32 + q4 * 8]);
#pragma unroll
            for (int i = 0; i < 4; i++)
#pragma unroll
                for (int j = 0; j < 4; j++)
                    acc[i][j] = __builtin_amdgcn_mfma_f32_16x16x32_bf16(af[i], bfv[j], acc[i][j], 0, 0, 0);
        }
        __syncthreads();
    }

    float bv[4];
    if (BIAS) {
#pragma unroll
        for (int j = 0; j < 4; j++) bv[j] = bias[col0 + wn * 64 + j * 16 + r];
    }
#pragma unroll
    for (int i = 0; i < 4; i++) {
#pragma unroll
        for (int j = 0; j < 4; j++) {
            int col = col0 + wn * 64 + j * 16 + r;
#pragma unroll
            for (int reg = 0; reg < 4; reg++) {
                int row = row0 + wm * 64 + i * 16 + q4 * 4 + reg;
                if (row < M) {
                    float v = acc[i][j][reg];
                    if (BIAS) v += bv[j];
                    if (OUTF32)
                        ((float*)Cv)[(size_t)blockIdx.z * strideC + (size_t)row * Nn + col] = v;
                    else
                        ((unsigned short*)Cv)[(size_t)blockIdx.z * strideC + (size_t)row * Nn + col] = f2bf(v);
                }
            }
        }
    }
}

// ----------------------- hierarchical sparse attention --------------------
// one block per (n, b); 4 waves; wave handles 4 heads; lane = dim within head
__global__ __launch_bounds__(256)
void attn_kernel(const unsigned short* __restrict__ Q, const unsigned short* __restrict__ K,
                 const unsigned short* __restrict__ V, unsigned short* __restrict__ O) {
    int n = blockIdx.x;
    int b = blockIdx.y;
    int tid = threadIdx.x;
    int wave = tid >> 6, lane = tid & 63;

    // tree neighbor rows (into xy's 4095-row sequence)
    int rows[NL];
    rows[0] = n;
    int cur = n;
#pragma unroll
    for (int l = 0; l < 11; l++) {
        cur = (l == 0) ? (cur ^ 1) : (((cur >> 1) + N_) ^ 1);
        rows[l + 1] = cur;
    }

    const unsigned short* Kb = K + (size_t)b * XYROWS * D_;
    const unsigned short* Vb = V + (size_t)b * XYROWS * D_;
    const size_t qrow = ((size_t)b * N_ + n) * D_;

#pragma unroll
    for (int hh = 0; hh < 4; hh++) {
        int h = wave * 4 + hh;
        int coff = h * DH_ + lane;
        float qv = bf2f(Q[qrow + coff]);
        float logits[NL];
#pragma unroll
        for (int j = 0; j < NL; j++) {
            float kv = bf2f(Kb[(size_t)rows[j] * D_ + coff]);
            float p = qv * kv;
#pragma unroll
            for (int m = 32; m >= 1; m >>= 1) p += __shfl_xor(p, m);
            logits[j] = p * 0.125f;   // 1/sqrt(64)
        }
        float mx = logits[0];
#pragma unroll
        for (int j = 1; j < NL; j++) mx = fmaxf(mx, logits[j]);
        float s = 0.f, w[NL];
#pragma unroll
        for (int j = 0; j < NL; j++) { w[j] = __expf(logits[j] - mx); s += w[j]; }
        float inv = 1.f / s;
        float acc = 0.f;
#pragma unroll
        for (int j = 0; j < NL; j++)
            acc += w[j] * bf2f(Vb[(size_t)rows[j] * D_ + coff]);
        O[qrow + coff] = f2bf(acc * inv);
    }
}

extern "C" void kernel_launch(void* const* d_in, const int* in_sizes, int n_in,
                              void* d_out, int out_size, void* d_ws, size_t ws_size,
                              hipStream_t stream) {
    const float* query = (const float*)d_in[0];
    // d_in[1] (key), d_in[2] (value) are unused by the reference
    const float* y  = (const float*)d_in[3];
    const float* Wq = (const float*)d_in[4];
    const float* Wk = (const float*)d_in[5];
    const float* Wv = (const float*)d_in[6];
    const float* Wo = (const float*)d_in[7];
    const float* bo = (const float*)d_in[8];
    float* out = (float*)d_out;

    char* ws = (char*)d_ws;
    size_t off = 0;
    auto alloc = [&](size_t bytes) {
        void* p = ws + off; off += (bytes + 255) & ~(size_t)255; return p;
    };
    unsigned short* xy  = (unsigned short*)alloc((size_t)B_ * XYROWS * D_ * 2);
    unsigned short* wqb = (unsigned short*)alloc((size_t)D_ * D_ * 2);
    unsigned short* wkb = (unsigned short*)alloc((size_t)D_ * D_ * 2);
    unsigned short* wvb = (unsigned short*)alloc((size_t)D_ * D_ * 2);
    unsigned short* wob = (unsigned short*)alloc((size_t)D_ * D_ * 2);
    unsigned short* Qb  = (unsigned short*)alloc((size_t)B_ * N_ * D_ * 2);
    unsigned short* Kb  = (unsigned short*)alloc((size_t)B_ * XYROWS * D_ * 2);
    unsigned short* Vb  = (unsigned short*)alloc((size_t)B_ * XYROWS * D_ * 2);
    unsigned short* At  = (unsigned short*)alloc((size_t)B_ * N_ * D_ * 2);

    // 1. build xy (bf16) and convert weights
    {
        int total = B_ * XYROWS * (D_ / 8);
        build_xy<<<(total + 255) / 256, 256, 0, stream>>>(query, y, xy);
        int wch = D_ * D_ / 8;
        int wblk = (wch + 255) / 256;
        cvt_bf16<<<wblk, 256, 0, stream>>>(Wq, wqb, wch);
        cvt_bf16<<<wblk, 256, 0, stream>>>(Wk, wkb, wch);
        cvt_bf16<<<wblk, 256, 0, stream>>>(Wv, wvb, wch);
        cvt_bf16<<<wblk, 256, 0, stream>>>(Wo, wob, wch);
    }

    // 2. Q projection: per-batch rows of xy (query part), batched via blockIdx.z
    {
        dim3 g(N_ / 128, 8, B_);
        gemm_bt<false, false><<<g, 256, 0, stream>>>(
            xy, wqb, Qb, nullptr, N_, (size_t)XYROWS * D_, (size_t)N_ * D_);
    }
    // 3. K and V projections over all xy rows (M = 8190, contiguous)
    {
        int M = B_ * XYROWS;
        dim3 g((M + 127) / 128, 8, 1);
        gemm_bt<false, false><<<g, 256, 0, stream>>>(xy, wkb, Kb, nullptr, M, 0, 0);
        gemm_bt<false, false><<<g, 256, 0, stream>>>(xy, wvb, Vb, nullptr, M, 0, 0);
    }
    // 4. hierarchical attention
    {
        dim3 g(N_, B_);
        attn_kernel<<<g, 256, 0, stream>>>(Qb, Kb, Vb, At);
    }
    // 5. output projection + bias (fp32 out)
    {
        dim3 g((B_ * N_) / 128, 8, 1);
        gemm_bt<true, true><<<g, 256, 0, stream>>>(At, wob, out, bo, B_ * N_, 0, 0);
    }
}

// Round 2
// 248.325 us; speedup vs baseline: 1.1586x; 1.1586x over previous
//
#include <hip/hip_runtime.h>
#include <hip/hip_bf16.h>
#include <cstdint>
#include <cstddef>

#define B_ 2
#define N_ 2048
#define D_ 1024
#define H_ 16
#define DH_ 64
#define XYROWS 4095   /* N + (N-1) */
#define NL 12         /* self + 11 tree neighbors */

typedef __attribute__((ext_vector_type(8))) short bf16x8;
typedef __attribute__((ext_vector_type(4))) float f32x4;

__device__ __forceinline__ float bf2f(unsigned short u) {
    union { unsigned int i; float f; } v; v.i = ((unsigned int)u) << 16; return v.f;
}
__device__ __forceinline__ float asf(unsigned int u) {
    union { unsigned int i; float f; } v; v.i = u; return v.f;
}
__device__ __forceinline__ unsigned short f2bf(float f) {
    union { float f; unsigned int i; } v; v.f = f;
    unsigned int u = v.i;
    unsigned int r = u + 0x7FFFu + ((u >> 16) & 1u);   // RNE
    return (unsigned short)(r >> 16);
}

// load 8 bf16 (16B) -> 8 fp32
__device__ __forceinline__ void ld8(const unsigned short* p, float* o) {
    uint4 u = *(const uint4*)p;
    o[0] = asf(u.x << 16); o[1] = asf(u.x & 0xffff0000u);
    o[2] = asf(u.y << 16); o[3] = asf(u.y & 0xffff0000u);
    o[4] = asf(u.z << 16); o[5] = asf(u.z & 0xffff0000u);
    o[6] = asf(u.w << 16); o[7] = asf(u.w & 0xffff0000u);
}

// ---------------- fp32 -> bf16 conversion (8 elems/thread) ----------------
__global__ void cvt_bf16(const float* __restrict__ src,
                         unsigned short* __restrict__ dst, int nchunks) {
    int c = blockIdx.x * blockDim.x + threadIdx.x;
    if (c >= nchunks) return;
    size_t i = (size_t)c * 8;
    float4 a = *(const float4*)(src + i);
    float4 b = *(const float4*)(src + i + 4);
    union { unsigned short us[8]; uint4 u4; } o;
    o.us[0] = f2bf(a.x); o.us[1] = f2bf(a.y); o.us[2] = f2bf(a.z); o.us[3] = f2bf(a.w);
    o.us[4] = f2bf(b.x); o.us[5] = f2bf(b.y); o.us[6] = f2bf(b.z); o.us[7] = f2bf(b.w);
    *(uint4*)(dst + i) = o.u4;
}

// ------------- build xy = concat(query, y) per batch, in bf16 -------------
__global__ void build_xy(const float* __restrict__ q, const float* __restrict__ y,
                         unsigned short* __restrict__ xy) {
    int c = blockIdx.x * blockDim.x + threadIdx.x;   // chunk of 8 elems
    int total = B_ * XYROWS * (D_ / 8);
    if (c >= total) return;
    int col8 = (c & (D_ / 8 - 1)) * 8;
    int rg = c >> 7;                                  // global row 0..B*4095-1
    int b = (rg >= XYROWS) ? 1 : 0;
    int r = rg - b * XYROWS;
    const float* src;
    if (r < N_) src = q + ((size_t)b * N_ + r) * D_ + col8;
    else        src = y + ((size_t)b * (N_ - 1) + (r - N_)) * D_ + col8;
    float4 a = *(const float4*)(src);
    float4 bb = *(const float4*)(src + 4);
    union { unsigned short us[8]; uint4 u4; } o;
    o.us[0] = f2bf(a.x);  o.us[1] = f2bf(a.y);  o.us[2] = f2bf(a.z);  o.us[3] = f2bf(a.w);
    o.us[4] = f2bf(bb.x); o.us[5] = f2bf(bb.y); o.us[6] = f2bf(bb.z); o.us[7] = f2bf(bb.w);
    *(uint4*)(xy + (size_t)rg * D_ + col8) = o.u4;
}

// --------------------------- bf16 GEMM: C = A @ W^T -----------------------
template<bool OUTF32, bool BIAS>
__global__ __launch_bounds__(256, 2)
void gemm_bt(const unsigned short* __restrict__ A, const unsigned short* __restrict__ W,
             void* __restrict__ Cv, const float* __restrict__ bias, int M,
             size_t strideA, size_t strideC) {
    constexpr int K = 1024, Nn = 1024;
    constexpr int BK = 64, LDSS = 72;
    __shared__ __align__(16) unsigned short la[128 * LDSS];
    __shared__ __align__(16) unsigned short lb[128 * LDSS];

    const unsigned short* Ab = A + (size_t)blockIdx.z * strideA;
    int tid = threadIdx.x;
    int row0 = blockIdx.x * 128;
    int col0 = blockIdx.y * 128;
    int wave = tid >> 6, lane = tid & 63;
    int wm = wave >> 1, wn = wave & 1;
    int q4 = lane >> 4, r = lane & 15;

    f32x4 acc[4][4];
    f32x4 zero = {0.f, 0.f, 0.f, 0.f};
#pragma unroll
    for (int i = 0; i < 4; i++)
#pragma unroll
        for (int j = 0; j < 4; j++) acc[i][j] = zero;

    for (int k0 = 0; k0 < K; k0 += BK) {
#pragma unroll
        for (int p = 0; p < 4; p++) {
            int slot = p * 256 + tid;
            int row = slot >> 3;
            int c8 = (slot & 7) * 8;
            int ar = row0 + row; if (ar >= M) ar = M - 1;
            uint4 va = *(const uint4*)(Ab + (size_t)ar * K + k0 + c8);
            uint4 vb = *(const uint4*)(W + (size_t)(col0 + row) * K + k0 + c8);
            *(uint4*)(&la[row * LDSS + c8]) = va;
            *(uint4*)(&lb[row * LDSS + c8]) = vb;
        }
        __syncthreads();
#pragma unroll
        for (int ks = 0; ks < 2; ks++) {
            bf16x8 af[4], bfv[4];
#pragma unroll
            for (int i = 0; i < 4; i++)
                af[i] = *(const bf16x8*)(&la[(wm * 64 + i * 16 + r) * LDSS + ks * 32 + q4 * 8]);
#pragma unroll
            for (int j = 0; j < 4; j++)
                bfv[j] = *(const bf16x8*)(&lb[(wn * 64 + j * 16 + r) * LDSS + ks * 32 + q4 * 8]);
#pragma unroll
            for (int i = 0; i < 4; i++)
#pragma unroll
                for (int j = 0; j < 4; j++)
                    acc[i][j] = __builtin_amdgcn_mfma_f32_16x16x32_bf16(af[i], bfv[j], acc[i][j], 0, 0, 0);
        }
        __syncthreads();
    }

    float bv[4];
    if (BIAS) {
#pragma unroll
        for (int j = 0; j < 4; j++) bv[j] = bias[col0 + wn * 64 + j * 16 + r];
    }
#pragma unroll
    for (int i = 0; i < 4; i++) {
#pragma unroll
        for (int j = 0; j < 4; j++) {
            int col = col0 + wn * 64 + j * 16 + r;
#pragma unroll
            for (int reg = 0; reg < 4; reg++) {
                int row = row0 + wm * 64 + i * 16 + q4 * 4 + reg;
                if (row < M) {
                    float v = acc[i][j][reg];
                    if (BIAS) v += bv[j];
                    if (OUTF32)
                        ((float*)Cv)[(size_t)blockIdx.z * strideC + (size_t)row * Nn + col] = v;
                    else
                        ((unsigned short*)Cv)[(size_t)blockIdx.z * strideC + (size_t)row * Nn + col] = f2bf(v);
                }
            }
        }
    }
}

// ----------------------- hierarchical sparse attention --------------------
// One block per (query-pair, batch). Queries 2i and 2i+1 attend to the SAME
// 12 rows (level-0 neighbors are each other; levels >=1 share the parent
// chain). half = t>>7 picks the query; c = t&127 picks an 8-dim chunk.
// All loads/stores are 16B/lane coalesced; dot reduces over 8 lanes.
__global__ __launch_bounds__(256)
void attn_kernel(const unsigned short* __restrict__ Q, const unsigned short* __restrict__ K,
                 const unsigned short* __restrict__ V, unsigned short* __restrict__ O) {
    int t = threadIdx.x;
    int half = t >> 7;           // which query of the pair
    int c = t & 127;             // 8-dim chunk 0..127
    int b = blockIdx.y;
    int n = blockIdx.x * 2 + half;

    int rows[NL];
    rows[0] = n;
    int cur = n ^ 1;
    rows[1] = cur;
#pragma unroll
    for (int l = 1; l < 11; l++) {
        cur = ((cur >> 1) + N_) ^ 1;
        rows[l + 1] = cur;
    }

    const unsigned short* Kb = K + (size_t)b * XYROWS * D_;
    const unsigned short* Vb = V + (size_t)b * XYROWS * D_;
    size_t qoff = ((size_t)b * N_ + n) * D_ + (size_t)c * 8;

    float q[8];
    ld8(Q + qoff, q);

    float logits[NL];
#pragma unroll
    for (int j = 0; j < NL; j++) {
        float kv[8];
        ld8(Kb + (size_t)rows[j] * D_ + (size_t)c * 8, kv);
        float p = 0.f;
#pragma unroll
        for (int e = 0; e < 8; e++) p = fmaf(q[e], kv[e], p);
        // head = c>>3: reduce across the 8 lanes of this head
        p += __shfl_xor(p, 1);
        p += __shfl_xor(p, 2);
        p += __shfl_xor(p, 4);
        logits[j] = p * 0.125f;   // 1/sqrt(64)
    }

    float mx = logits[0];
#pragma unroll
    for (int j = 1; j < NL; j++) mx = fmaxf(mx, logits[j]);
    float s = 0.f, w[NL];
#pragma unroll
    for (int j = 0; j < NL; j++) { w[j] = __expf(logits[j] - mx); s += w[j]; }
    float inv = 1.f / s;

    float acc[8] = {0.f, 0.f, 0.f, 0.f, 0.f, 0.f, 0.f, 0.f};
#pragma unroll
    for (int j = 0; j < NL; j++) {
        float vv[8];
        ld8(Vb + (size_t)rows[j] * D_ + (size_t)c * 8, vv);
        float wj = w[j] * inv;
#pragma unroll
        for (int e = 0; e < 8; e++) acc[e] = fmaf(wj, vv[e], acc[e]);
    }

    union { unsigned short us[8]; uint4 u4; } o;
#pragma unroll
    for (int e = 0; e < 8; e++) o.us[e] = f2bf(acc[e]);
    *(uint4*)(O + qoff) = o.u4;
}

extern "C" void kernel_launch(void* const* d_in, const int* in_sizes, int n_in,
                              void* d_out, int out_size, void* d_ws, size_t ws_size,
                              hipStream_t stream) {
    const float* query = (const float*)d_in[0];
    // d_in[1] (key), d_in[2] (value) are unused by the reference
    const float* y  = (const float*)d_in[3];
    const float* Wq = (const float*)d_in[4];
    const float* Wk = (const float*)d_in[5];
    const float* Wv = (const float*)d_in[6];
    const float* Wo = (const float*)d_in[7];
    const float* bo = (const float*)d_in[8];
    float* out = (float*)d_out;

    char* ws = (char*)d_ws;
    size_t off = 0;
    auto alloc = [&](size_t bytes) {
        void* p = ws + off; off += (bytes + 255) & ~(size_t)255; return p;
    };
    unsigned short* xy  = (unsigned short*)alloc((size_t)B_ * XYROWS * D_ * 2);
    unsigned short* wqb = (unsigned short*)alloc((size_t)D_ * D_ * 2);
    unsigned short* wkb = (unsigned short*)alloc((size_t)D_ * D_ * 2);
    unsigned short* wvb = (unsigned short*)alloc((size_t)D_ * D_ * 2);
    unsigned short* wob = (unsigned short*)alloc((size_t)D_ * D_ * 2);
    unsigned short* Qb  = (unsigned short*)alloc((size_t)B_ * N_ * D_ * 2);
    unsigned short* Kb  = (unsigned short*)alloc((size_t)B_ * XYROWS * D_ * 2);
    unsigned short* Vb  = (unsigned short*)alloc((size_t)B_ * XYROWS * D_ * 2);
    unsigned short* At  = (unsigned short*)alloc((size_t)B_ * N_ * D_ * 2);

    // 1. build xy (bf16) and convert weights
    {
        int total = B_ * XYROWS * (D_ / 8);
        build_xy<<<(total + 255) / 256, 256, 0, stream>>>(query, y, xy);
        int wch = D_ * D_ / 8;
        int wblk = (wch + 255) / 256;
        cvt_bf16<<<wblk, 256, 0, stream>>>(Wq, wqb, wch);
        cvt_bf16<<<wblk, 256, 0, stream>>>(Wk, wkb, wch);
        cvt_bf16<<<wblk, 256, 0, stream>>>(Wv, wvb, wch);
        cvt_bf16<<<wblk, 256, 0, stream>>>(Wo, wob, wch);
    }

    // 2. Q projection
    {
        dim3 g(N_ / 128, 8, B_);
        gemm_bt<false, false><<<g, 256, 0, stream>>>(
            xy, wqb, Qb, nullptr, N_, (size_t)XYROWS * D_, (size_t)N_ * D_);
    }
    // 3. K and V projections over all xy rows (M = 8190, contiguous)
    {
        int M = B_ * XYROWS;
        dim3 g((M + 127) / 128, 8, 1);
        gemm_bt<false, false><<<g, 256, 0, stream>>>(xy, wkb, Kb, nullptr, M, 0, 0);
        gemm_bt<false, false><<<g, 256, 0, stream>>>(xy, wvb, Vb, nullptr, M, 0, 0);
    }
    // 4. hierarchical attention (paired queries)
    {
        dim3 g(N_ / 2, B_);
        attn_kernel<<<g, 256, 0, stream>>>(Qb, Kb, Vb, At);
    }
    // 5. output projection + bias (fp32 out)
    {
        dim3 g((B_ * N_) / 128, 8, 1);
        gemm_bt<true, true><<<g, 256, 0, stream>>>(At, wob, out, bo, B_ * N_, 0, 0);
    }
}

// Round 3
// 228.305 us; speedup vs baseline: 1.2602x; 1.0877x over previous
//
#include <hip/hip_runtime.h>
#include <hip/hip_bf16.h>
#include <cstdint>
#include <cstddef>

#define B_ 2
#define N_ 2048
#define D_ 1024
#define H_ 16
#define DH_ 64
#define XYROWS 4095   /* N + (N-1) */
#define NL 12         /* self + 11 tree neighbors */
#define QKVN 3072     /* packed Q|K|V projection width */

typedef __attribute__((ext_vector_type(8))) short bf16x8;
typedef __attribute__((ext_vector_type(4))) float f32x4;

__device__ __forceinline__ float asf(unsigned int u) {
    union { unsigned int i; float f; } v; v.i = u; return v.f;
}
__device__ __forceinline__ unsigned short f2bf(float f) {
    union { float f; unsigned int i; } v; v.f = f;
    unsigned int u = v.i;
    unsigned int r = u + 0x7FFFu + ((u >> 16) & 1u);   // RNE
    return (unsigned short)(r >> 16);
}

// load 8 bf16 (16B) -> 8 fp32
__device__ __forceinline__ void ld8(const unsigned short* p, float* o) {
    uint4 u = *(const uint4*)p;
    o[0] = asf(u.x << 16); o[1] = asf(u.x & 0xffff0000u);
    o[2] = asf(u.y << 16); o[3] = asf(u.y & 0xffff0000u);
    o[4] = asf(u.z << 16); o[5] = asf(u.z & 0xffff0000u);
    o[6] = asf(u.w << 16); o[7] = asf(u.w & 0xffff0000u);
}

// async global->LDS 16B per lane; lds base must be wave-uniform, HW scatters
// lane l's 16B to base + l*16.
__device__ __forceinline__ void gload_lds16(const unsigned short* g, unsigned short* l) {
    __builtin_amdgcn_global_load_lds(
        (const __attribute__((address_space(1))) unsigned int*)g,
        (__attribute__((address_space(3))) unsigned int*)l,
        16, 0, 0);
}

// ---- convert all four weight matrices in ONE launch ----
// Wq,Wk,Wv -> packed wqkv[3072][1024]; Wo -> wob[1024][1024]
__global__ void cvt_weights(const float* __restrict__ Wq, const float* __restrict__ Wk,
                            const float* __restrict__ Wv, const float* __restrict__ Wo,
                            unsigned short* __restrict__ wqkv, unsigned short* __restrict__ wob) {
    int c = blockIdx.x * blockDim.x + threadIdx.x;   // chunk of 8 elems
    int which = c >> 17;                             // 131072 chunks per 1M-elem weight
    int idx = c & 131071;
    const float* src = (which == 0) ? Wq : (which == 1) ? Wk : (which == 2) ? Wv : Wo;
    unsigned short* dst = (which < 3) ? (wqkv + (size_t)which * D_ * D_) : wob;
    size_t i = (size_t)idx * 8;
    float4 a = *(const float4*)(src + i);
    float4 b = *(const float4*)(src + i + 4);
    union { unsigned short us[8]; uint4 u4; } o;
    o.us[0] = f2bf(a.x); o.us[1] = f2bf(a.y); o.us[2] = f2bf(a.z); o.us[3] = f2bf(a.w);
    o.us[4] = f2bf(b.x); o.us[5] = f2bf(b.y); o.us[6] = f2bf(b.z); o.us[7] = f2bf(b.w);
    *(uint4*)(dst + i) = o.u4;
}

// ------------- build xy = concat(query, y) per batch, in bf16 -------------
__global__ void build_xy(const float* __restrict__ q, const float* __restrict__ y,
                         unsigned short* __restrict__ xy) {
    int c = blockIdx.x * blockDim.x + threadIdx.x;   // chunk of 8 elems
    int total = B_ * XYROWS * (D_ / 8);
    if (c >= total) return;
    int col8 = (c & (D_ / 8 - 1)) * 8;
    int rg = c >> 7;                                  // global row 0..B*4095-1
    int b = (rg >= XYROWS) ? 1 : 0;
    int r = rg - b * XYROWS;
    const float* src;
    if (r < N_) src = q + ((size_t)b * N_ + r) * D_ + col8;
    else        src = y + ((size_t)b * (N_ - 1) + (r - N_)) * D_ + col8;
    float4 a = *(const float4*)(src);
    float4 bb = *(const float4*)(src + 4);
    union { unsigned short us[8]; uint4 u4; } o;
    o.us[0] = f2bf(a.x);  o.us[1] = f2bf(a.y);  o.us[2] = f2bf(a.z);  o.us[3] = f2bf(a.w);
    o.us[4] = f2bf(bb.x); o.us[5] = f2bf(bb.y); o.us[6] = f2bf(bb.z); o.us[7] = f2bf(bb.w);
    *(uint4*)(xy + (size_t)rg * D_ + col8) = o.u4;
}

// --------------------------- bf16 GEMM: C = A @ W^T -----------------------
// A: M x 1024 bf16 row-major; W: Nn x 1024 bf16 row-major (rows = out feat).
// 128x128 block tile, 4 waves (2x2), 64x64/wave via 4x4 MFMA 16x16x32.
// m97-style staging: global_load_lds width=16 into unpadded 128x64 tiles.
template<bool OUTF32, bool BIAS>
__global__ __launch_bounds__(256, 2)
void gemm_bt(const unsigned short* __restrict__ A, const unsigned short* __restrict__ W,
             void* __restrict__ Cv, const float* __restrict__ bias, int M, int Nn) {
    constexpr int K = 1024, BK = 64;
    __shared__ __align__(16) unsigned short la[128 * 64];
    __shared__ __align__(16) unsigned short lb[128 * 64];

    int tid = threadIdx.x;
    int row0 = blockIdx.x * 128;
    int col0 = blockIdx.y * 128;
    int wave = tid >> 6, lane = tid & 63;
    int wm = wave >> 1, wn = wave & 1;
    int q4 = lane >> 4, r = lane & 15;

    // staging coords: lane l supplies row l/8 (within 8-row segment), chunk l%8
    int rseg = lane >> 3;          // 0..7
    int cseg = (lane & 7) * 8;     // ushort col 0..56

    f32x4 acc[4][4];
    f32x4 zero = {0.f, 0.f, 0.f, 0.f};
#pragma unroll
    for (int i = 0; i < 4; i++)
#pragma unroll
        for (int j = 0; j < 4; j++) acc[i][j] = zero;

    for (int k0 = 0; k0 < K; k0 += BK) {
#pragma unroll
        for (int p = 0; p < 4; p++) {
            int seg = wave * 4 + p;              // 0..15: 8-row segment of the tile
            int rloc = seg * 8 + rseg;           // 0..127
            int ar = row0 + rloc; if (ar >= M) ar = M - 1;
            gload_lds16(A + (size_t)ar * K + k0 + cseg, &la[seg * 512]);
            gload_lds16(W + (size_t)(col0 + rloc) * K + k0 + cseg, &lb[seg * 512]);
        }
        __syncthreads();
#pragma unroll
        for (int ks = 0; ks < 2; ks++) {
            bf16x8 af[4], bfv[4];
#pragma unroll
            for (int i = 0; i < 4; i++)
                af[i] = *(const bf16x8*)(&la[(wm * 64 + i * 16 + r) * 64 + ks * 32 + q4 * 8]);
#pragma unroll
            for (int j = 0; j < 4; j++)
                bfv[j] = *(const bf16x8*)(&lb[(wn * 64 + j * 16 + r) * 64 + ks * 32 + q4 * 8]);
#pragma unroll
            for (int i = 0; i < 4; i++)
#pragma unroll
                for (int j = 0; j < 4; j++)
                    acc[i][j] = __builtin_amdgcn_mfma_f32_16x16x32_bf16(af[i], bfv[j], acc[i][j], 0, 0, 0);
        }
        __syncthreads();
    }

    float bv[4];
    if (BIAS) {
#pragma unroll
        for (int j = 0; j < 4; j++) bv[j] = bias[col0 + wn * 64 + j * 16 + r];
    }
#pragma unroll
    for (int i = 0; i < 4; i++) {
#pragma unroll
        for (int j = 0; j < 4; j++) {
            int col = col0 + wn * 64 + j * 16 + r;
#pragma unroll
            for (int reg = 0; reg < 4; reg++) {
                int row = row0 + wm * 64 + i * 16 + q4 * 4 + reg;
                if (row < M) {
                    float v = acc[i][j][reg];
                    if (BIAS) v += bv[j];
                    if (OUTF32)
                        ((float*)Cv)[(size_t)row * Nn + col] = v;
                    else
                        ((unsigned short*)Cv)[(size_t)row * Nn + col] = f2bf(v);
                }
            }
        }
    }
}

// ----------------------- hierarchical sparse attention --------------------
// One block per (query-pair, batch); queries 2i,2i+1 share all 12 rows.
// QKV layout: per xy-row, 3072 cols = [Q | K | V].
__global__ __launch_bounds__(256)
void attn_kernel(const unsigned short* __restrict__ QKV, unsigned short* __restrict__ O) {
    int t = threadIdx.x;
    int half = t >> 7;           // which query of the pair
    int c = t & 127;             // 8-dim chunk 0..127
    int b = blockIdx.y;
    int n = blockIdx.x * 2 + half;

    int rows[NL];
    rows[0] = n;
    int cur = n ^ 1;
    rows[1] = cur;
#pragma unroll
    for (int l = 1; l < 11; l++) {
        cur = ((cur >> 1) + N_) ^ 1;
        rows[l + 1] = cur;
    }

    const unsigned short* base = QKV + (size_t)b * XYROWS * QKVN;
    size_t c8 = (size_t)c * 8;

    float q[8];
    ld8(base + (size_t)n * QKVN + c8, q);

    float logits[NL];
#pragma unroll
    for (int j = 0; j < NL; j++) {
        float kv[8];
        ld8(base + (size_t)rows[j] * QKVN + D_ + c8, kv);
        float p = 0.f;
#pragma unroll
        for (int e = 0; e < 8; e++) p = fmaf(q[e], kv[e], p);
        p += __shfl_xor(p, 1);
        p += __shfl_xor(p, 2);
        p += __shfl_xor(p, 4);
        logits[j] = p * 0.125f;   // 1/sqrt(64)
    }

    float mx = logits[0];
#pragma unroll
    for (int j = 1; j < NL; j++) mx = fmaxf(mx, logits[j]);
    float s = 0.f, w[NL];
#pragma unroll
    for (int j = 0; j < NL; j++) { w[j] = __expf(logits[j] - mx); s += w[j]; }
    float inv = 1.f / s;

    float acc[8] = {0.f, 0.f, 0.f, 0.f, 0.f, 0.f, 0.f, 0.f};
#pragma unroll
    for (int j = 0; j < NL; j++) {
        float vv[8];
        ld8(base + (size_t)rows[j] * QKVN + 2 * D_ + c8, vv);
        float wj = w[j] * inv;
#pragma unroll
        for (int e = 0; e < 8; e++) acc[e] = fmaf(wj, vv[e], acc[e]);
    }

    union { unsigned short us[8]; uint4 u4; } o;
#pragma unroll
    for (int e = 0; e < 8; e++) o.us[e] = f2bf(acc[e]);
    *(uint4*)(O + ((size_t)b * N_ + n) * D_ + c8) = o.u4;
}

extern "C" void kernel_launch(void* const* d_in, const int* in_sizes, int n_in,
                              void* d_out, int out_size, void* d_ws, size_t ws_size,
                              hipStream_t stream) {
    const float* query = (const float*)d_in[0];
    // d_in[1] (key), d_in[2] (value) are unused by the reference
    const float* y  = (const float*)d_in[3];
    const float* Wq = (const float*)d_in[4];
    const float* Wk = (const float*)d_in[5];
    const float* Wv = (const float*)d_in[6];
    const float* Wo = (const float*)d_in[7];
    const float* bo = (const float*)d_in[8];
    float* out = (float*)d_out;

    char* ws = (char*)d_ws;
    size_t off = 0;
    auto alloc = [&](size_t bytes) {
        void* p = ws + off; off += (bytes + 255) & ~(size_t)255; return p;
    };
    unsigned short* xy   = (unsigned short*)alloc((size_t)B_ * XYROWS * D_ * 2 + 4096); // +pad for OOB-clamped tile rows
    unsigned short* wqkv = (unsigned short*)alloc((size_t)QKVN * D_ * 2);
    unsigned short* wob  = (unsigned short*)alloc((size_t)D_ * D_ * 2);
    unsigned short* QKV  = (unsigned short*)alloc((size_t)B_ * XYROWS * QKVN * 2);
    unsigned short* At   = (unsigned short*)alloc((size_t)B_ * N_ * D_ * 2);

    // 1. build xy (bf16) + convert all weights (one launch each)
    {
        int total = B_ * XYROWS * (D_ / 8);
        build_xy<<<(total + 255) / 256, 256, 0, stream>>>(query, y, xy);
        cvt_weights<<<2048, 256, 0, stream>>>(Wq, Wk, Wv, Wo, wqkv, wob);
    }
    // 2. fused QKV projection: all 8190 xy rows x packed [Wq|Wk|Wv]
    {
        dim3 g((B_ * XYROWS + 127) / 128, QKVN / 128);
        gemm_bt<false, false><<<g, 256, 0, stream>>>(
            xy, wqkv, QKV, nullptr, B_ * XYROWS, QKVN);
    }
    // 3. hierarchical attention (paired queries)
    {
        dim3 g(N_ / 2, B_);
        attn_kernel<<<g, 256, 0, stream>>>(QKV, At);
    }
    // 4. output projection + bias (fp32 out)
    {
        dim3 g((B_ * N_) / 128, D_ / 128);
        gemm_bt<true, true><<<g, 256, 0, stream>>>(At, wob, out, bo, B_ * N_, D_);
    }
}

// Round 4
// 200.989 us; speedup vs baseline: 1.4315x; 1.1359x over previous
//
#include <hip/hip_runtime.h>
#include <hip/hip_bf16.h>
#include <cstdint>
#include <cstddef>

#define B_ 2
#define N_ 2048
#define D_ 1024
#define H_ 16
#define DH_ 64
#define XYROWS 4095   /* N + (N-1) */
#define NL 12         /* self + 11 tree neighbors */
#define QKVN 3072     /* packed Q|K|V projection width */

typedef __attribute__((ext_vector_type(8))) short bf16x8;
typedef __attribute__((ext_vector_type(4))) float f32x4;

__device__ __forceinline__ float asf(unsigned int u) {
    union { unsigned int i; float f; } v; v.i = u; return v.f;
}
__device__ __forceinline__ unsigned short f2bf(float f) {
    union { float f; unsigned int i; } v; v.f = f;
    unsigned int u = v.i;
    unsigned int r = u + 0x7FFFu + ((u >> 16) & 1u);   // RNE
    return (unsigned short)(r >> 16);
}

// load 8 bf16 (16B) -> 8 fp32
__device__ __forceinline__ void ld8(const unsigned short* p, float* o) {
    uint4 u = *(const uint4*)p;
    o[0] = asf(u.x << 16); o[1] = asf(u.x & 0xffff0000u);
    o[2] = asf(u.y << 16); o[3] = asf(u.y & 0xffff0000u);
    o[4] = asf(u.z << 16); o[5] = asf(u.z & 0xffff0000u);
    o[6] = asf(u.w << 16); o[7] = asf(u.w & 0xffff0000u);
}

// async global->LDS 16B per lane; lds base wave-uniform, HW scatters lane l
// to base + l*16.
__device__ __forceinline__ void gload_lds16(const unsigned short* g, unsigned short* l) {
    __builtin_amdgcn_global_load_lds(
        (const __attribute__((address_space(1))) unsigned int*)g,
        (__attribute__((address_space(3))) unsigned int*)l,
        16, 0, 0);
}

// ---- fused prep: build xy (bf16) + convert all four weight matrices ----
__global__ void prep_kernel(const float* __restrict__ q, const float* __restrict__ y,
                            const float* __restrict__ Wq, const float* __restrict__ Wk,
                            const float* __restrict__ Wv, const float* __restrict__ Wo,
                            unsigned short* __restrict__ xy,
                            unsigned short* __restrict__ wqkv, unsigned short* __restrict__ wob) {
    int c = blockIdx.x * blockDim.x + threadIdx.x;   // chunk of 8 elems
    constexpr int TOTAL_XY = B_ * XYROWS * (D_ / 8); // 1048320
    constexpr int TOTAL_W  = 4 * 131072;             // 524288
    if (c >= TOTAL_XY + TOTAL_W) return;
    const float* src;
    unsigned short* dst;
    if (c < TOTAL_XY) {
        int col8 = (c & (D_ / 8 - 1)) * 8;
        int rg = c >> 7;                              // global row 0..B*4095-1
        int b = (rg >= XYROWS) ? 1 : 0;
        int r = rg - b * XYROWS;
        if (r < N_) src = q + ((size_t)b * N_ + r) * D_ + col8;
        else        src = y + ((size_t)b * (N_ - 1) + (r - N_)) * D_ + col8;
        dst = xy + (size_t)rg * D_ + col8;
    } else {
        int idx = c - TOTAL_XY;
        int which = idx >> 17;
        int sub = idx & 131071;
        const float* w = (which == 0) ? Wq : (which == 1) ? Wk : (which == 2) ? Wv : Wo;
        src = w + (size_t)sub * 8;
        dst = ((which < 3) ? (wqkv + (size_t)which * D_ * D_) : wob) + (size_t)sub * 8;
    }
    float4 a = *(const float4*)(src);
    float4 bb = *(const float4*)(src + 4);
    union { unsigned short us[8]; uint4 u4; } o;
    o.us[0] = f2bf(a.x);  o.us[1] = f2bf(a.y);  o.us[2] = f2bf(a.z);  o.us[3] = f2bf(a.w);
    o.us[4] = f2bf(bb.x); o.us[5] = f2bf(bb.y); o.us[6] = f2bf(bb.z); o.us[7] = f2bf(bb.w);
    *(uint4*)(dst) = o.u4;
}

// --------------------------- bf16 GEMM: C = A @ W^T -----------------------
// A: M x 1024 bf16 row-major; W: Nn x 1024 bf16 row-major.
// BM x 128 block tile, 4 waves (2x2), (BM/2)x64 per wave via MFMA 16x16x32.
// Staging: global_load_lds width=16, XOR-swizzled chunk order so the
// ds_read_b128 fragment reads hit all 32 banks (2-way max = free).
// QSKIP: for the packed QKV weight, skip Q columns (col0<1024) on row tiles
// that contain only y-positions (no query rows).
template<int BM, bool OUTF32, bool BIAS, bool QSKIP>
__global__ __launch_bounds__(256, 2)
void gemm_bt(const unsigned short* __restrict__ A, const unsigned short* __restrict__ W,
             void* __restrict__ Cv, const float* __restrict__ bias, int M, int Nn) {
    constexpr int K = 1024, BK = 64;
    constexpr int IM = BM / 32;          // mfma row-tiles per wave
    __shared__ __align__(16) unsigned short la[BM * 64];
    __shared__ __align__(16) unsigned short lb[128 * 64];

    int row0 = blockIdx.x * BM;
    int col0 = blockIdx.y * 128;
    if (QSKIP && col0 < 1024) {
        int t = blockIdx.x;                       // y-only row tiles (BM=128):
        if ((t >= 16 && t <= 30) || t >= 48) return;
    }
    int tid = threadIdx.x;
    int wave = tid >> 6, lane = tid & 63;
    int wm = wave >> 1, wn = wave & 1;
    int q4 = lane >> 4, r = lane & 15;

    // staging: lane l supplies row l/8 of its segment; fetched chunk is
    // XOR-swizzled by the row's low 3 bits.
    int rsub = lane >> 3;                         // 0..7
    int csw = ((lane & 7) ^ rsub) * 8;            // swizzled source chunk col

    f32x4 acc[IM][4];
    f32x4 zero = {0.f, 0.f, 0.f, 0.f};
#pragma unroll
    for (int i = 0; i < IM; i++)
#pragma unroll
        for (int j = 0; j < 4; j++) acc[i][j] = zero;

    for (int k0 = 0; k0 < K; k0 += BK) {
#pragma unroll
        for (int p = 0; p < IM; p++) {            // A: BM/8 segs, IM per wave
            int seg = wave * IM + p;
            int ar = row0 + seg * 8 + rsub; if (ar >= M) ar = M - 1;
            gload_lds16(A + (size_t)ar * K + k0 + csw, &la[seg * 512]);
        }
#pragma unroll
        for (int p = 0; p < 4; p++) {             // B: 16 segs, 4 per wave
            int seg = wave * 4 + p;
            gload_lds16(W + (size_t)(col0 + seg * 8 + rsub) * K + k0 + csw, &lb[seg * 512]);
        }
        __syncthreads();
#pragma unroll
        for (int ks = 0; ks < 2; ks++) {
            int cidx = ks * 4 + q4;
            bf16x8 af[IM], bfv[4];
#pragma unroll
            for (int i = 0; i < IM; i++) {
                int rr = wm * (BM / 2) + i * 16 + r;
                af[i] = *(const bf16x8*)(&la[rr * 64 + ((cidx ^ (rr & 7)) << 3)]);
            }
#pragma unroll
            for (int j = 0; j < 4; j++) {
                int rb = wn * 64 + j * 16 + r;
                bfv[j] = *(const bf16x8*)(&lb[rb * 64 + ((cidx ^ (rb & 7)) << 3)]);
            }
#pragma unroll
            for (int i = 0; i < IM; i++)
#pragma unroll
                for (int j = 0; j < 4; j++)
                    acc[i][j] = __builtin_amdgcn_mfma_f32_16x16x32_bf16(af[i], bfv[j], acc[i][j], 0, 0, 0);
        }
        __syncthreads();
    }

    float bv[4];
    if (BIAS) {
#pragma unroll
        for (int j = 0; j < 4; j++) bv[j] = bias[col0 + wn * 64 + j * 16 + r];
    }
#pragma unroll
    for (int i = 0; i < IM; i++) {
#pragma unroll
        for (int j = 0; j < 4; j++) {
            int col = col0 + wn * 64 + j * 16 + r;
#pragma unroll
            for (int reg = 0; reg < 4; reg++) {
                int row = row0 + wm * (BM / 2) + i * 16 + q4 * 4 + reg;
                if (row < M) {
                    float v = acc[i][j][reg];
                    if (BIAS) v += bv[j];
                    if (OUTF32)
                        ((float*)Cv)[(size_t)row * Nn + col] = v;
                    else
                        ((unsigned short*)Cv)[(size_t)row * Nn + col] = f2bf(v);
                }
            }
        }
    }
}

// ----------------------- hierarchical sparse attention --------------------
// One block per (query-pair, batch); queries 2i,2i+1 share all 12 rows.
// QKV layout: per xy-row, 3072 cols = [Q | K | V].
__global__ __launch_bounds__(256)
void attn_kernel(const unsigned short* __restrict__ QKV, unsigned short* __restrict__ O) {
    int t = threadIdx.x;
    int half = t >> 7;           // which query of the pair
    int c = t & 127;             // 8-dim chunk 0..127
    int b = blockIdx.y;
    int n = blockIdx.x * 2 + half;

    int rows[NL];
    rows[0] = n;
    int cur = n ^ 1;
    rows[1] = cur;
#pragma unroll
    for (int l = 1; l < 11; l++) {
        cur = ((cur >> 1) + N_) ^ 1;
        rows[l + 1] = cur;
    }

    const unsigned short* base = QKV + (size_t)b * XYROWS * QKVN;
    size_t c8 = (size_t)c * 8;

    float q[8];
    ld8(base + (size_t)n * QKVN + c8, q);

    float logits[NL];
#pragma unroll
    for (int j = 0; j < NL; j++) {
        float kv[8];
        ld8(base + (size_t)rows[j] * QKVN + D_ + c8, kv);
        float p = 0.f;
#pragma unroll
        for (int e = 0; e < 8; e++) p = fmaf(q[e], kv[e], p);
        p += __shfl_xor(p, 1);
        p += __shfl_xor(p, 2);
        p += __shfl_xor(p, 4);
        logits[j] = p * 0.125f;   // 1/sqrt(64)
    }

    float mx = logits[0];
#pragma unroll
    for (int j = 1; j < NL; j++) mx = fmaxf(mx, logits[j]);
    float s = 0.f, w[NL];
#pragma unroll
    for (int j = 0; j < NL; j++) { w[j] = __expf(logits[j] - mx); s += w[j]; }
    float inv = 1.f / s;

    float acc[8] = {0.f, 0.f, 0.f, 0.f, 0.f, 0.f, 0.f, 0.f};
#pragma unroll
    for (int j = 0; j < NL; j++) {
        float vv[8];
        ld8(base + (size_t)rows[j] * QKVN + 2 * D_ + c8, vv);
        float wj = w[j] * inv;
#pragma unroll
        for (int e = 0; e < 8; e++) acc[e] = fmaf(wj, vv[e], acc[e]);
    }

    union { unsigned short us[8]; uint4 u4; } o;
#pragma unroll
    for (int e = 0; e < 8; e++) o.us[e] = f2bf(acc[e]);
    *(uint4*)(O + ((size_t)b * N_ + n) * D_ + c8) = o.u4;
}

extern "C" void kernel_launch(void* const* d_in, const int* in_sizes, int n_in,
                              void* d_out, int out_size, void* d_ws, size_t ws_size,
                              hipStream_t stream) {
    const float* query = (const float*)d_in[0];
    // d_in[1] (key), d_in[2] (value) are unused by the reference
    const float* y  = (const float*)d_in[3];
    const float* Wq = (const float*)d_in[4];
    const float* Wk = (const float*)d_in[5];
    const float* Wv = (const float*)d_in[6];
    const float* Wo = (const float*)d_in[7];
    const float* bo = (const float*)d_in[8];
    float* out = (float*)d_out;

    char* ws = (char*)d_ws;
    size_t off = 0;
    auto alloc = [&](size_t bytes) {
        void* p = ws + off; off += (bytes + 255) & ~(size_t)255; return p;
    };
    unsigned short* xy   = (unsigned short*)alloc((size_t)B_ * XYROWS * D_ * 2 + 4096);
    unsigned short* wqkv = (unsigned short*)alloc((size_t)QKVN * D_ * 2);
    unsigned short* wob  = (unsigned short*)alloc((size_t)D_ * D_ * 2);
    unsigned short* QKV  = (unsigned short*)alloc((size_t)B_ * XYROWS * QKVN * 2);
    unsigned short* At   = (unsigned short*)alloc((size_t)B_ * N_ * D_ * 2);

    // 1. fused prep: xy (bf16) + all weight conversions
    prep_kernel<<<6144, 256, 0, stream>>>(query, y, Wq, Wk, Wv, Wo, xy, wqkv, wob);

    // 2. fused QKV projection (skips Q cols on y-only row tiles)
    {
        dim3 g((B_ * XYROWS + 127) / 128, QKVN / 128);
        gemm_bt<128, false, false, true><<<g, 256, 0, stream>>>(
            xy, wqkv, QKV, nullptr, B_ * XYROWS, QKVN);
    }
    // 3. hierarchical attention (paired queries)
    {
        dim3 g(N_ / 2, B_);
        attn_kernel<<<g, 256, 0, stream>>>(QKV, At);
    }
    // 4. output projection + bias (fp32 out), 64-row tiles -> 512 blocks
    {
        dim3 g((B_ * N_) / 64, D_ / 128);
        gemm_bt<64, true, true, false><<<g, 256, 0, stream>>>(At, wob, out, bo, B_ * N_, D_);
    }
}